// Round 1
// baseline (1338.895 us; speedup 1.0000x reference)
//
#include <hip/hip_runtime.h>
#include <hip/hip_bf16.h>

// Problem constants
#define L_ 768
#define C_ 64
#define E_ 1024
#define EPS_ 1e-5f

static __device__ __forceinline__ float bf2f(unsigned short u) {
  return __uint_as_float(((unsigned int)u) << 16);
}
static __device__ __forceinline__ unsigned short f2bf(float f) {
  unsigned int u = __float_as_uint(f);
  u += 0x7FFFu + ((u >> 16) & 1u);   // RNE
  return (unsigned short)(u >> 16);
}

// ---------------------------------------------------------------------------
// K1: a[b,l,d] = sum_e x[b,l,e] * W_sl[d,e] + b_sl[d]    (tiny GEMM)
// grid = B*L = 1536 blocks, 256 threads
// ---------------------------------------------------------------------------
__global__ __launch_bounds__(256) void k1_proj(
    const float* __restrict__ x, const float* __restrict__ Wsl,
    const float* __restrict__ bsl, float* __restrict__ a) {
  __shared__ float xr[1024];
  __shared__ float red[256];
  const int bl = blockIdx.x;
  const int tid = threadIdx.x;
  for (int idx = tid; idx < 1024; idx += 256)
    xr[idx] = x[(size_t)bl * 1024 + idx];
  __syncthreads();
  const int d = tid & 63, q = tid >> 6;
  const float* w = Wsl + (size_t)d * 1024 + q * 256;
  const float* xq = &xr[q * 256];
  float s = 0.f;
#pragma unroll 8
  for (int e = 0; e < 256; ++e) s += w[e] * xq[e];
  red[tid] = s;
  __syncthreads();
  if (tid < 64) {
    a[(size_t)bl * 64 + tid] =
        red[tid] + red[64 + tid] + red[128 + tid] + red[192 + tid] + bsl[tid];
  }
}

// ---------------------------------------------------------------------------
// K2: per (b,i,jblock of 64): t[j,c] = sum_d (a_i[d]*a_j[d]) * W_op[c,d] + b_op
//     -> LayerNorm over c -> xp = x_pairwise + LN  (stored bf16)
// 256 threads: 16(tj) x 16(tc), micro tile 4j x 4c. grid = 2*768*12 = 18432
// ---------------------------------------------------------------------------
__global__ __launch_bounds__(256) void k2_outer(
    const float* __restrict__ xpw, const float* __restrict__ a,
    const float* __restrict__ Wop, const float* __restrict__ bop,
    const float* __restrict__ lnw, const float* __restrict__ lnb,
    unsigned short* __restrict__ xp) {
  __shared__ float Pl[64 * 68];      // P^T: [d][j], padded stride 68
  __shared__ float Wt[64 * 64];      // W^T: [d][c]
  __shared__ float ai[64];
  __shared__ float reds[2 * 1088];   // [s1|s2][(jj*16+tc)*17+tj]
  __shared__ float muv[128];         // per local-j: mean, rsqrt
  const int tid = threadIdx.x;
  const int bx = blockIdx.x;
  const int jblk = bx % 12;
  const int i = (bx / 12) % 768;
  const int b = bx / (12 * 768);
  const int jb = jblk * 64;

  if (tid < 64) ai[tid] = a[(size_t)(b * 768 + i) * 64 + tid];
  __syncthreads();
  for (int idx = tid; idx < 4096; idx += 256) {
    int jj = idx >> 6, d = idx & 63;
    Pl[d * 68 + jj] = a[(size_t)(b * 768 + jb + jj) * 64 + d] * ai[d];
  }
  for (int idx = tid; idx < 4096; idx += 256) {
    int d = idx >> 6, c = idx & 63;
    Wt[d * 64 + c] = Wop[c * 64 + d];
  }
  __syncthreads();

  const int tj = tid & 15, tc = tid >> 4;
  float acc[4][4];
#pragma unroll
  for (int u = 0; u < 4; ++u)
#pragma unroll
    for (int v = 0; v < 4; ++v) acc[u][v] = 0.f;

#pragma unroll 8
  for (int d = 0; d < 64; ++d) {
    const float4 pj = *(const float4*)&Pl[d * 68 + 4 * tj];
    const float4 wc = *(const float4*)&Wt[d * 64 + 4 * tc];
    const float pjv[4] = {pj.x, pj.y, pj.z, pj.w};
    const float wcv[4] = {wc.x, wc.y, wc.z, wc.w};
#pragma unroll
    for (int jj = 0; jj < 4; ++jj)
#pragma unroll
      for (int cc = 0; cc < 4; ++cc) acc[jj][cc] += pjv[jj] * wcv[cc];
  }

  float bop4[4], lw4[4], lb4[4];
#pragma unroll
  for (int cc = 0; cc < 4; ++cc) {
    int c = 4 * tc + cc;
    bop4[cc] = bop[c];
    lw4[cc] = lnw[c];
    lb4[cc] = lnb[c];
  }
#pragma unroll
  for (int jj = 0; jj < 4; ++jj) {
    float s1 = 0.f, s2 = 0.f;
#pragma unroll
    for (int cc = 0; cc < 4; ++cc) {
      float t = acc[jj][cc] + bop4[cc];
      acc[jj][cc] = t;
      s1 += t;
      s2 += t * t;
    }
    reds[(jj * 16 + tc) * 17 + tj] = s1;
    reds[1088 + (jj * 16 + tc) * 17 + tj] = s2;
  }
  __syncthreads();
  if (tid < 64) {
    int tjj = tid >> 2, jj = tid & 3;   // local j = 4*tjj + jj = tid
    float m = 0.f, v = 0.f;
#pragma unroll
    for (int k = 0; k < 16; ++k) {
      m += reds[(jj * 16 + k) * 17 + tjj];
      v += reds[1088 + (jj * 16 + k) * 17 + tjj];
    }
    m *= (1.f / 64.f);
    v = v * (1.f / 64.f) - m * m;
    muv[tid * 2] = m;
    muv[tid * 2 + 1] = rsqrtf(v + EPS_);
  }
  __syncthreads();

  float m4[4], rs4[4];
#pragma unroll
  for (int jj = 0; jj < 4; ++jj) {
    int jl = 4 * tj + jj;
    m4[jj] = muv[jl * 2];
    rs4[jj] = muv[jl * 2 + 1];
  }

#pragma unroll
  for (int cc = 0; cc < 4; ++cc) {
    int c = 4 * tc + cc;
    size_t base = ((size_t)(b * 64 + c) * 768 + i) * 768 + jb + 4 * tj;
    float4 xv = *(const float4*)&xpw[base];
    float xa[4] = {xv.x, xv.y, xv.z, xv.w};
    ushort4 uo;
    unsigned short* up = (unsigned short*)&uo;
#pragma unroll
    for (int jj = 0; jj < 4; ++jj) {
      float y = (acc[jj][cc] - m4[jj]) * rs4[jj] * lw4[cc] + lb4[cc];
      up[jj] = f2bf(xa[jj] + y);
    }
    *(ushort4*)&xp[base] = uo;
  }
}

// ---------------------------------------------------------------------------
// K3: GN statistics: h = dwconv3x3(xp) (SAME, zero-pad), accumulate
// sum(h), sum(h^2) per (b, group=c>>1) via atomics.
// block per (b, c, 32-row tile): grid = 2*64*24 = 3072, 256 threads
// ---------------------------------------------------------------------------
__global__ __launch_bounds__(256) void k3_stats(
    const unsigned short* __restrict__ xp, const float* __restrict__ dww,
    float* __restrict__ stats) {
  __shared__ unsigned short buf[34 * 770];
  __shared__ float wsum1[4], wsum2[4];
  const int tid = threadIdx.x;
  const int bx = blockIdx.x;
  const int it = bx % 24;
  const int c = (bx / 24) & 63;
  const int b = bx / (24 * 64);
  const int i0 = it * 32;

  for (int idx = tid; idx < 34 * 768; idx += 256) {
    int r = idx / 768;
    int j = idx - r * 768;
    int gi = i0 - 1 + r;
    unsigned short v = 0;
    if (gi >= 0 && gi < 768)
      v = xp[((size_t)(b * 64 + c) * 768 + gi) * 768 + j];
    buf[r * 770 + 1 + j] = v;
  }
  if (tid < 68) buf[(tid >> 1) * 770 + (tid & 1) * 769] = 0;
  float w[9];
#pragma unroll
  for (int k = 0; k < 9; ++k) w[k] = dww[c * 9 + k];
  __syncthreads();

  float s1 = 0.f, s2 = 0.f;
  for (int ir = 0; ir < 32; ++ir) {
#pragma unroll
    for (int jj = 0; jj < 3; ++jj) {
      int j = tid + jj * 256;
      const unsigned short* r0 = &buf[ir * 770 + j];
      const unsigned short* r1 = r0 + 770;
      const unsigned short* r2 = r1 + 770;
      float h = w[0] * bf2f(r0[0]) + w[1] * bf2f(r0[1]) + w[2] * bf2f(r0[2]) +
                w[3] * bf2f(r1[0]) + w[4] * bf2f(r1[1]) + w[5] * bf2f(r1[2]) +
                w[6] * bf2f(r2[0]) + w[7] * bf2f(r2[1]) + w[8] * bf2f(r2[2]);
      s1 += h;
      s2 += h * h;
    }
  }
#pragma unroll
  for (int off = 32; off >= 1; off >>= 1) {
    s1 += __shfl_xor(s1, off);
    s2 += __shfl_xor(s2, off);
  }
  if ((tid & 63) == 0) {
    wsum1[tid >> 6] = s1;
    wsum2[tid >> 6] = s2;
  }
  __syncthreads();
  if (tid == 0) {
    float t1 = wsum1[0] + wsum1[1] + wsum1[2] + wsum1[3];
    float t2 = wsum2[0] + wsum2[1] + wsum2[2] + wsum2[3];
    int g = c >> 1;
    atomicAdd(&stats[(b * 32 + g) * 2 + 0], t1);
    atomicAdd(&stats[(b * 32 + g) * 2 + 1], t2);
  }
}

// ---------------------------------------------------------------------------
// K3b: per (b,c) GN scale/bias: A = rs_g*gn_w[c], B = gn_b[c] - m_g*A
// ---------------------------------------------------------------------------
__global__ void k3b_affine(const float* __restrict__ stats,
                           const float* __restrict__ gnw,
                           const float* __restrict__ gnb,
                           float* __restrict__ af) {
  int tid = threadIdx.x;
  if (tid >= 128) return;
  int b = tid >> 6, c = tid & 63, g = c >> 1;
  float s1 = stats[(b * 32 + g) * 2];
  float s2 = stats[(b * 32 + g) * 2 + 1];
  const float N = 2.f * 768.f * 768.f;
  float m = s1 / N;
  float v = s2 / N - m * m;
  float rs = rsqrtf(v + EPS_);
  float A = rs * gnw[c];
  af[(b * 64 + c) * 2] = A;
  af[(b * 64 + c) * 2 + 1] = gnb[c] - m * A;
}

// ---------------------------------------------------------------------------
// K4: per (b, 8-row x 32-col tile, all 64 ch):
//   stage xp tile+halo -> dwconv -> GN affine -> GELU -> g (LDS, c-major)
//   -> 1x1 conv -> + xp + pw_b -> out
// grid = 2*96*24 = 4608, 512 threads
// ---------------------------------------------------------------------------
__global__ __launch_bounds__(512) void k4_final(
    const unsigned short* __restrict__ xp, const float* __restrict__ af,
    const float* __restrict__ dww, const float* __restrict__ pww,
    const float* __restrict__ pwb, float* __restrict__ out) {
  __shared__ unsigned short xps[64 * 10 * 36 + 16];  // [c][10][36] (stride pad)
  __shared__ unsigned short gls[64 * 258];           // [ci][pix(256)+pad]
  __shared__ unsigned short pwT[64 * 64];            // [ci][co] bf16
  __shared__ float dwl[576];
  __shared__ float afl[128];
  __shared__ float pwbl[64];
  const int tid = threadIdx.x;
  const int bx = blockIdx.x;
  const int jt = bx % 24;
  const int it = (bx / 24) % 96;
  const int b = bx / (24 * 96);
  const int i0 = it * 8, j0 = jt * 32;

  for (int idx = tid; idx < 64 * 10 * 34; idx += 512) {
    int c = idx / 340;
    int rem = idx - c * 340;
    int r = rem / 34;
    int jj = rem - r * 34;
    int gi = i0 - 1 + r, gj = j0 - 1 + jj;
    unsigned short v = 0;
    if (gi >= 0 && gi < 768 && gj >= 0 && gj < 768)
      v = xp[((size_t)(b * 64 + c) * 768 + gi) * 768 + gj];
    xps[(c * 10 + r) * 36 + jj] = v;
  }
  for (int idx = tid; idx < 4096; idx += 512) {
    int ci = idx >> 6, co = idx & 63;
    pwT[ci * 64 + co] = f2bf(pww[co * 64 + ci]);
  }
  for (int idx = tid; idx < 576; idx += 512) dwl[idx] = dww[idx];
  if (tid < 128) afl[tid] = af[b * 128 + tid];
  if (tid < 64) pwbl[tid] = pwb[tid];
  __syncthreads();

  // phase 1: depthwise 3x3 + GN affine + exact GELU -> gls (bf16)
  {
    const int c = tid >> 3;
    const int q = tid & 7;  // j base = q*4
    const float* w = &dwl[c * 9];
    const float A = afl[c * 2], Bv = afl[c * 2 + 1];
    const unsigned short* base = &xps[(c * 10) * 36 + q * 4];
    float r0[8], r1[8], r2[8];
    {
      ushort4 u0 = *(const ushort4*)(base);
      ushort4 u1 = *(const ushort4*)(base + 4);
      r0[0] = bf2f(u0.x); r0[1] = bf2f(u0.y); r0[2] = bf2f(u0.z); r0[3] = bf2f(u0.w);
      r0[4] = bf2f(u1.x); r0[5] = bf2f(u1.y); r0[6] = bf2f(u1.z); r0[7] = bf2f(u1.w);
      u0 = *(const ushort4*)(base + 36);
      u1 = *(const ushort4*)(base + 36 + 4);
      r1[0] = bf2f(u0.x); r1[1] = bf2f(u0.y); r1[2] = bf2f(u0.z); r1[3] = bf2f(u0.w);
      r1[4] = bf2f(u1.x); r1[5] = bf2f(u1.y); r1[6] = bf2f(u1.z); r1[7] = bf2f(u1.w);
    }
#pragma unroll
    for (int r = 0; r < 8; ++r) {
      ushort4 u0 = *(const ushort4*)(base + (r + 2) * 36);
      ushort4 u1 = *(const ushort4*)(base + (r + 2) * 36 + 4);
      r2[0] = bf2f(u0.x); r2[1] = bf2f(u0.y); r2[2] = bf2f(u0.z); r2[3] = bf2f(u0.w);
      r2[4] = bf2f(u1.x); r2[5] = bf2f(u1.y); r2[6] = bf2f(u1.z); r2[7] = bf2f(u1.w);
      ushort4 go;
      unsigned short* gp = (unsigned short*)&go;
#pragma unroll
      for (int jj = 0; jj < 4; ++jj) {
        float h = w[0] * r0[jj] + w[1] * r0[jj + 1] + w[2] * r0[jj + 2] +
                  w[3] * r1[jj] + w[4] * r1[jj + 1] + w[5] * r1[jj + 2] +
                  w[6] * r2[jj] + w[7] * r2[jj + 1] + w[8] * r2[jj + 2];
        float z = A * h + Bv;
        float gv = 0.5f * z * (1.f + erff(z * 0.70710678118654752f));
        gp[jj] = f2bf(gv);
      }
      *(ushort4*)&gls[c * 258 + r * 32 + q * 4] = go;
#pragma unroll
      for (int k = 0; k < 8; ++k) { r0[k] = r1[k]; r1[k] = r2[k]; }
    }
  }
  __syncthreads();

  // phase 2: 1x1 conv. thread = (pg 0..63 pixel-group of 4, cg 0..7 -> 8 co)
  const int pg = tid & 63;
  const int cg = tid >> 6;
  float acc[8][4];
#pragma unroll
  for (int s = 0; s < 8; ++s)
#pragma unroll
    for (int p = 0; p < 4; ++p) acc[s][p] = 0.f;

#pragma unroll 4
  for (int ci = 0; ci < 64; ++ci) {
    ushort4 gu = *(const ushort4*)&gls[ci * 258 + pg * 4];
    float gv[4] = {bf2f(gu.x), bf2f(gu.y), bf2f(gu.z), bf2f(gu.w)};
    ushort4 p0 = *(const ushort4*)&pwT[ci * 64 + cg * 8];
    ushort4 p1 = *(const ushort4*)&pwT[ci * 64 + cg * 8 + 4];
    float pv[8] = {bf2f(p0.x), bf2f(p0.y), bf2f(p0.z), bf2f(p0.w),
                   bf2f(p1.x), bf2f(p1.y), bf2f(p1.z), bf2f(p1.w)};
#pragma unroll
    for (int s = 0; s < 8; ++s)
#pragma unroll
      for (int p = 0; p < 4; ++p) acc[s][p] += pv[s] * gv[p];
  }

  // phase 3: out = xp + (1x1 + bias)
  const int pix0 = pg * 4;
  const int r = pix0 >> 5;
  const int jc = pix0 & 31;
#pragma unroll
  for (int s = 0; s < 8; ++s) {
    int co = cg * 8 + s;
    float pb = pwbl[co];
    const unsigned short* xc = &xps[(co * 10 + 1 + r) * 36 + 1 + jc];
    float4 o;
    o.x = bf2f(xc[0]) + acc[s][0] + pb;
    o.y = bf2f(xc[1]) + acc[s][1] + pb;
    o.z = bf2f(xc[2]) + acc[s][2] + pb;
    o.w = bf2f(xc[3]) + acc[s][3] + pb;
    size_t oaddr = ((size_t)(b * 64 + co) * 768 + i0 + r) * 768 + j0 + jc;
    *(float4*)&out[oaddr] = o;
  }
}

// ---------------------------------------------------------------------------
extern "C" void kernel_launch(void* const* d_in, const int* in_sizes, int n_in,
                              void* d_out, int out_size, void* d_ws,
                              size_t ws_size, hipStream_t stream) {
  const float* x_pw = (const float*)d_in[0];
  const float* x    = (const float*)d_in[1];
  const float* Wsl  = (const float*)d_in[2];
  const float* bsl  = (const float*)d_in[3];
  const float* Wop  = (const float*)d_in[4];
  const float* bop  = (const float*)d_in[5];
  const float* lnw  = (const float*)d_in[6];
  const float* lnb  = (const float*)d_in[7];
  const float* dww  = (const float*)d_in[8];
  const float* gnw  = (const float*)d_in[9];
  const float* gnb  = (const float*)d_in[10];
  const float* pww  = (const float*)d_in[11];
  const float* pwb  = (const float*)d_in[12];
  float* out = (float*)d_out;

  char* ws = (char*)d_ws;
  float* a_buf  = (float*)(ws);                  // 393216 B
  float* stats  = (float*)(ws + 393216);         // 512 B  (sum, sumsq per b,g)
  float* affine = (float*)(ws + 393216 + 512);   // 1024 B (A,B per b,c)
  unsigned short* xpbuf = (unsigned short*)(ws + 458752);  // 151 MB bf16

  hipMemsetAsync(stats, 0, 512, stream);
  k1_proj<<<2 * 768, 256, 0, stream>>>(x, Wsl, bsl, a_buf);
  k2_outer<<<2 * 768 * 12, 256, 0, stream>>>(x_pw, a_buf, Wop, bop, lnw, lnb,
                                             xpbuf);
  k3_stats<<<2 * 64 * 24, 256, 0, stream>>>(xpbuf, dww, stats);
  k3b_affine<<<1, 128, 0, stream>>>(stats, gnw, gnb, affine);
  k4_final<<<2 * 96 * 24, 512, 0, stream>>>(xpbuf, affine, dww, pww, pwb, out);
}